// Round 21
// baseline (15.713 us; speedup 1.0000x reference)
//
#include <hip/hip_runtime.h>
#include <float.h>
#include <math.h>

// Problem constants (from reference)
constexpr int B  = 16;
constexpr int VS = 10475;
constexpr int VO = 8192;
constexpr int K  = 64;
constexpr int PS = 1024;
constexpr int PO = 2048;

// R21 = R20 with mfma_f32_32x32x8_f16 (K=8) -- our augmented dot is 8-dim,
// so the x16 variant wasted k8-15 (zeros from lanes 32-63). Now ALL lanes
// carry real fragments:
//   lanes 0-31 : k0-3 = A(hi(s),-1) / B(o,w2h)
//   lanes 32-63: k4-7 = A(lo(s),-1) / B(o,w2l)
// Per tile: 1 ds_read_b64 (8 B/lane) + 1 MFMA (half the FLOP of x16) +
// 16 v_min(-d). dot = s.o_hat - 0.5|o_hat|^2 = -t (numerics identical to
// R18-R20, absmax 0 verified). C/D layout (32x32 shape, m74/m101):
// col=lane&31, row=(reg&3)+8*(reg>>2)+4*(lane>>5) -> epilogue = R20.
constexpr int BLK  = 512;
constexpr int QPB  = 256;              // queries per block
constexpr int GRID = K * (PS / QPB);   // 256
constexpr int NW   = 8;                // waves per block
constexpr int NT   = PO / 32;          // 64 tiles per wave

typedef float  v3f    __attribute__((ext_vector_type(3)));
typedef float  f32x16 __attribute__((ext_vector_type(16)));
typedef _Float16 half4 __attribute__((ext_vector_type(4)));
typedef unsigned int u32;
typedef u32 v4u __attribute__((ext_vector_type(4)));

__device__ __forceinline__ u32 pkh(_Float16 lo, _Float16 hi) {
    const unsigned short l = __builtin_bit_cast(unsigned short, lo);
    const unsigned short h = __builtin_bit_cast(unsigned short, hi);
    return ((u32)h << 16) | (u32)l;
}

// ---------------- kernel 1: full min + block partial sum ----------------

__global__ __launch_bounds__(BLK)
void cl_onepass(const float* __restrict__ smplx_v,
                const float* __restrict__ object_v,
                const int*   __restrict__ spi,
                const int*   __restrict__ opi,
                const int*   __restrict__ bidx,
                float*       __restrict__ partial)   // [GRID]
{
    __shared__ u32   so[PO * 4];     // 32 KiB: entry j = [o,w2h | o,w2l] fp16
    __shared__ float wsum[NW];

    const int bk   = blockIdx.x;
    const int tid  = threadIdx.x;
    const int k    = bk >> 2;
    const int ic   = bk & 3;
    const int b    = bidx[k];
    const int wave = tid >> 6;            // qgroup 0..7
    const int lane = tid & 63;

    // ---- stage objects: 4/thread, dwordx3, fp16-round + w2 hi/lo split ----
    const float* __restrict__ ov = object_v + (size_t)b * VO * 3;
    #pragma unroll
    for (int r = 0; r < PO / BLK; ++r) {
        const int j  = r * BLK + tid;
        const int oj = opi[k * PO + j];
        const v3f p  = *(const v3f*)(ov + 3 * (size_t)oj);
        const _Float16 hx = (_Float16)p.x, hy = (_Float16)p.y, hz = (_Float16)p.z;
        const float fx = (float)hx, fy = (float)hy, fz = (float)hz;
        const float w2 = 0.5f * (fx * fx + fy * fy + fz * fz);
        const _Float16 w2h = (_Float16)w2;
        const _Float16 w2l = (_Float16)(w2 - (float)w2h);
        const u32 d0 = pkh(hx, hy);
        *(v4u*)&so[j * 4] = (v4u){d0, pkh(hz, w2h), d0, pkh(hz, w2l)};
    }

    // ---- queries: ALL lanes load query (lane&31); hi/lo half by lane>>5 ----
    const int q  = lane & 31;
    const int i  = ic * QPB + wave * 32 + q;
    const int si = spi[k * PS + i];
    const v3f s  = *(const v3f*)(smplx_v + 3 * ((size_t)b * VS + si));
    const float s2 = s.x * s.x + s.y * s.y + s.z * s.z;
    const _Float16 shx = (_Float16)s.x, shy = (_Float16)s.y, shz = (_Float16)s.z;
    const _Float16 n1  = (_Float16)(-1.0f);
    half4 afrag;
    if (lane < 32) {
        afrag = (half4){shx, shy, shz, n1};
    } else {
        afrag = (half4){(_Float16)(s.x - (float)shx),
                        (_Float16)(s.y - (float)shy),
                        (_Float16)(s.z - (float)shz), n1};
    }
    __syncthreads();

    // ---- per-lane B pointer: col = lane&31, k-half = lane>>5 ----
    const u32* bp = &so[(lane & 31) * 4 + (lane >> 5) * 2];

    // ---- hot loop: 64 tiles, 1 ds_read_b64 + 1 MFMA(32x32x8) + 16 v_min ----
    f32x16 mint;
    #pragma unroll
    for (int ii = 0; ii < 16; ++ii) mint[ii] = FLT_MAX;

    #pragma unroll 4
    for (int t = 0; t < NT; ++t) {
        const half4 bfrag = *(const half4*)bp;
        f32x16 zc;
        #pragma unroll
        for (int ii = 0; ii < 16; ++ii) zc[ii] = 0.0f;
        const f32x16 d = __builtin_amdgcn_mfma_f32_32x32x8f16(
            afrag, bfrag, zc, 0, 0, 0);
        #pragma unroll
        for (int ii = 0; ii < 16; ++ii) mint[ii] = fminf(mint[ii], -d[ii]);
        bp += 32 * 4;                     // 32 entries x 4 u32 per tile
    }

    // ---- per-row min over 32 cols (xor within each 32-lane half) ----
    #pragma unroll
    for (int m = 1; m <= 16; m <<= 1) {
        #pragma unroll
        for (int ii = 0; ii < 16; ++ii)
            mint[ii] = fminf(mint[ii], __shfl_xor(mint[ii], m, 64));
    }

    // ---- route row l's min to lane l (static select + 2 shuffles, R20) ----
    // row = (reg&3) + 8*(reg>>2) + 4*h  =>  reg(l) = (l&3) | ((l>>3)<<2),
    // h(l) = (l>>2)&1. Lane 32+l holds the same reg(l) for half 1.
    const int mm  = lane & 31;
    const int reg = (mm & 3) | ((mm >> 3) << 2);
    float sel = mint[0];
    #pragma unroll
    for (int r = 1; r < 16; ++r) sel = (reg == r) ? mint[r] : sel;
    const float vA = __shfl(sel, mm, 64);        // half-0 value for reg(mm)
    const float vB = __shfl(sel, mm + 32, 64);   // half-1 value for reg(mm)
    const float d2m = ((mm >> 2) & 1) ? vB : vA;

    float d = 0.0f;
    if (lane < 32)
        d = sqrtf(fmaxf(fmaf(2.0f, d2m, s2), 0.0f));

    // ---- wave sum (lanes 0-31 carry values) ----
    #pragma unroll
    for (int m = 1; m <= 16; m <<= 1)
        d += __shfl_xor(d, m, 64);
    if (lane == 0) wsum[wave] = d;
    __syncthreads();

    if (tid < 64) {
        float v = (tid < NW) ? wsum[tid] : 0.0f;
        #pragma unroll
        for (int off = 4; off > 0; off >>= 1)
            v += __shfl_down(v, off, 64);
        if (tid == 0) partial[bk] = v;
    }
}

// ---------------- kernel 2: final 256 -> 1 reduce (one wave) ----------------

__global__ __launch_bounds__(64)
void cl_final(const float* __restrict__ partial, float* __restrict__ out)
{
    const int t = threadIdx.x;
    const float4 a = ((const float4*)partial)[t];   // 64 lanes x 4 = 256
    float v = (a.x + a.y) + (a.z + a.w);
    #pragma unroll
    for (int off = 32; off > 0; off >>= 1)
        v += __shfl_down(v, off, 64);
    if (t == 0) out[0] = v * (1.0f / (float)(K * PS));
}

// ---------------- launcher ----------------

extern "C" void kernel_launch(void* const* d_in, const int* in_sizes, int n_in,
                              void* d_out, int out_size, void* d_ws, size_t ws_size,
                              hipStream_t stream)
{
    const float* smplx_v       = (const float*)d_in[0];
    const float* object_v      = (const float*)d_in[1];
    const int*   smpl_part_idx = (const int*)d_in[2];
    const int*   obj_part_idx  = (const int*)d_in[3];
    const int*   batch_idx     = (const int*)d_in[4];
    float*       out           = (float*)d_out;

    float* partial = (float*)d_ws;   // GRID floats

    cl_onepass<<<GRID, BLK, 0, stream>>>(
        smplx_v, object_v, smpl_part_idx, obj_part_idx, batch_idx, partial);
    cl_final<<<1, 64, 0, stream>>>(partial, out);
}

// Round 22
// 15.548 us; speedup vs baseline: 1.0106x; 1.0106x over previous
//
#include <hip/hip_runtime.h>
#include <float.h>
#include <math.h>

// Problem constants (from reference)
constexpr int B  = 16;
constexpr int VS = 10475;
constexpr int VO = 8192;
constexpr int K  = 64;
constexpr int PS = 1024;
constexpr int PO = 2048;

// R22 = R20 (15.68us: 256 blocks x 512 thr, wave = 32 queries x all objects,
// mfma_f32_32x32x16_f16, shuffle-only epilogue) + DOUBLE-BUFFERED object
// gather: stage half-0, issue half-1's global loads, compute half-0 tiles
// while the loads fly, write half-1, barrier, compute half-1. Hot loop /
// epilogue byte-identical to R20.
constexpr int BLK  = 512;
constexpr int QPB  = 256;              // queries per block
constexpr int GRID = K * (PS / QPB);   // 256
constexpr int NW   = 8;                // waves per block
constexpr int HALF = PO / 2;           // 1024 objects per half
constexpr int NTH  = HALF / 32;        // 32 tiles per half per wave
constexpr int OPT  = HALF / BLK;       // 2 points per thread per half

typedef float  v3f    __attribute__((ext_vector_type(3)));
typedef float  f32x16 __attribute__((ext_vector_type(16)));
typedef _Float16 half8 __attribute__((ext_vector_type(8)));
typedef unsigned int u32;
typedef u32 v4u __attribute__((ext_vector_type(4)));

__device__ __forceinline__ u32 pkh(_Float16 lo, _Float16 hi) {
    const unsigned short l = __builtin_bit_cast(unsigned short, lo);
    const unsigned short h = __builtin_bit_cast(unsigned short, hi);
    return ((u32)h << 16) | (u32)l;
}

__device__ __forceinline__ v4u mk_entry(const v3f p) {
    const _Float16 hx = (_Float16)p.x, hy = (_Float16)p.y, hz = (_Float16)p.z;
    const float fx = (float)hx, fy = (float)hy, fz = (float)hz;
    const float w2 = 0.5f * (fx * fx + fy * fy + fz * fz);
    const _Float16 w2h = (_Float16)w2;
    const _Float16 w2l = (_Float16)(w2 - (float)w2h);
    const u32 d0 = pkh(hx, hy);
    return (v4u){d0, pkh(hz, w2h), d0, pkh(hz, w2l)};
}

// ---------------- kernel 1: full min + block partial sum ----------------

__global__ __launch_bounds__(BLK)
void cl_onepass(const float* __restrict__ smplx_v,
                const float* __restrict__ object_v,
                const int*   __restrict__ spi,
                const int*   __restrict__ opi,
                const int*   __restrict__ bidx,
                float*       __restrict__ partial)   // [GRID]
{
    __shared__ u32   so[(PO + 16) * 4];   // 33 KiB entries + zero pad
    __shared__ float wsum[NW];

    const int bk   = blockIdx.x;
    const int tid  = threadIdx.x;
    const int k    = bk >> 2;
    const int ic   = bk & 3;
    const int b    = bidx[k];
    const int wave = tid >> 6;            // qgroup 0..7
    const int lane = tid & 63;

    const float* __restrict__ ov   = object_v + (size_t)b * VO * 3;
    const int*   __restrict__ opik = opi + k * PO;

    // ---- stage half-0 (entries 0..HALF-1), 2 points/thread, dwordx3 ----
    #pragma unroll
    for (int r = 0; r < OPT; ++r) {
        const int j  = r * BLK + tid;
        const int oj = opik[j];
        const v3f p  = *(const v3f*)(ov + 3 * (size_t)oj);
        *(v4u*)&so[j * 4] = mk_entry(p);
    }
    if (tid < 64) so[PO * 4 + tid] = 0;   // zero pad (lanes>=32 B-frag)

    // ---- queries: lanes 0-31 load query wave*32+lane (overlaps gather) ----
    half8 afrag = (half8)(_Float16)0;
    float s2 = 0.0f;
    if (lane < 32) {
        const int i  = ic * QPB + wave * 32 + lane;
        const int si = spi[k * PS + i];
        const v3f s  = *(const v3f*)(smplx_v + 3 * ((size_t)b * VS + si));
        s2 = s.x * s.x + s.y * s.y + s.z * s.z;
        const _Float16 shx = (_Float16)s.x, shy = (_Float16)s.y, shz = (_Float16)s.z;
        const _Float16 slx = (_Float16)(s.x - (float)shx);
        const _Float16 sly = (_Float16)(s.y - (float)shy);
        const _Float16 slz = (_Float16)(s.z - (float)shz);
        const _Float16 n1  = (_Float16)(-1.0f);
        afrag = (half8){shx, shy, shz, n1, slx, sly, slz, n1};
    }

    // ---- issue half-1 loads (in flight under half-0 compute) ----
    v3f p1[OPT];
    #pragma unroll
    for (int r = 0; r < OPT; ++r) {
        const int oj = opik[HALF + r * BLK + tid];
        p1[r] = *(const v3f*)(ov + 3 * (size_t)oj);
    }
    __syncthreads();

    // ---- hot loop setup ----
    const int  boff = (lane < 32) ? (lane & 31) * 4 : PO * 4;
    const int  inc  = (lane < 32) ? 32 * 4 : 0;   // u32 stride per tile

    f32x16 mint;
    #pragma unroll
    for (int i = 0; i < 16; ++i) mint[i] = FLT_MAX;

    #define CL_TILES(BASE)                                                    \
    {                                                                         \
        const u32* bp = &so[(BASE) + boff];                                   \
        _Pragma("unroll 4")                                                   \
        for (int t = 0; t < NTH; ++t) {                                       \
            const half8 bfrag = *(const half8*)bp;                            \
            f32x16 zc;                                                        \
            _Pragma("unroll")                                                 \
            for (int i = 0; i < 16; ++i) zc[i] = 0.0f;                        \
            const f32x16 d = __builtin_amdgcn_mfma_f32_32x32x16_f16(          \
                afrag, bfrag, zc, 0, 0, 0);                                   \
            _Pragma("unroll")                                                 \
            for (int i = 0; i < 16; ++i) mint[i] = fminf(mint[i], -d[i]);     \
            bp += inc;                                                        \
        }                                                                     \
    }

    CL_TILES(0)                          // half-0; half-1 loads in flight

    // ---- write half-1 (waitcnt lands here), then visibility barrier ----
    #pragma unroll
    for (int r = 0; r < OPT; ++r) {
        const int j = HALF + r * BLK + tid;
        *(v4u*)&so[j * 4] = mk_entry(p1[r]);
    }
    __syncthreads();

    CL_TILES(HALF * 4)                   // half-1
    #undef CL_TILES

    // ---- per-row min over 32 cols (xor within each 32-lane half) ----
    #pragma unroll
    for (int m = 1; m <= 16; m <<= 1) {
        #pragma unroll
        for (int i = 0; i < 16; ++i)
            mint[i] = fminf(mint[i], __shfl_xor(mint[i], m, 64));
    }

    // ---- route row l's min to lane l (static select + 2 shuffles, R20) ----
    const int mm  = lane & 31;
    const int reg = (mm & 3) | ((mm >> 3) << 2);
    float sel = mint[0];
    #pragma unroll
    for (int r = 1; r < 16; ++r) sel = (reg == r) ? mint[r] : sel;
    const float vA = __shfl(sel, mm, 64);        // half-0 value for reg(mm)
    const float vB = __shfl(sel, mm + 32, 64);   // half-1 value for reg(mm)
    const float d2m = ((mm >> 2) & 1) ? vB : vA;

    float d = 0.0f;
    if (lane < 32)
        d = sqrtf(fmaxf(fmaf(2.0f, d2m, s2), 0.0f));

    // ---- wave sum (lanes 0-31 carry values) ----
    #pragma unroll
    for (int m = 1; m <= 16; m <<= 1)
        d += __shfl_xor(d, m, 64);
    if (lane == 0) wsum[wave] = d;
    __syncthreads();

    if (tid < 64) {
        float v = (tid < NW) ? wsum[tid] : 0.0f;
        #pragma unroll
        for (int off = 4; off > 0; off >>= 1)
            v += __shfl_down(v, off, 64);
        if (tid == 0) partial[bk] = v;
    }
}

// ---------------- kernel 2: final 256 -> 1 reduce (one wave) ----------------

__global__ __launch_bounds__(64)
void cl_final(const float* __restrict__ partial, float* __restrict__ out)
{
    const int t = threadIdx.x;
    const float4 a = ((const float4*)partial)[t];   // 64 lanes x 4 = 256
    float v = (a.x + a.y) + (a.z + a.w);
    #pragma unroll
    for (int off = 32; off > 0; off >>= 1)
        v += __shfl_down(v, off, 64);
    if (t == 0) out[0] = v * (1.0f / (float)(K * PS));
}

// ---------------- launcher ----------------

extern "C" void kernel_launch(void* const* d_in, const int* in_sizes, int n_in,
                              void* d_out, int out_size, void* d_ws, size_t ws_size,
                              hipStream_t stream)
{
    const float* smplx_v       = (const float*)d_in[0];
    const float* object_v      = (const float*)d_in[1];
    const int*   smpl_part_idx = (const int*)d_in[2];
    const int*   obj_part_idx  = (const int*)d_in[3];
    const int*   batch_idx     = (const int*)d_in[4];
    float*       out           = (float*)d_out;

    float* partial = (float*)d_ws;   // GRID floats

    cl_onepass<<<GRID, BLK, 0, stream>>>(
        smplx_v, object_v, smpl_part_idx, obj_part_idx, batch_idx, partial);
    cl_final<<<1, 64, 0, stream>>>(partial, out);
}